// Round 2
// baseline (607.682 us; speedup 1.0000x reference)
//
#include <hip/hip_runtime.h>
#include <math.h>

#define B_N 16
#define C_IN 64
#define H_N 128
#define W_N 128
#define C_OUT 128

// ---------------------------------------------------------------------------
// Prep: scalars qe=exp(q), pe=exp(p), nk=||w||_F into d_ws[0..2]
// ---------------------------------------------------------------------------
__global__ __launch_bounds__(256) void scs_prep(
    const float* __restrict__ w, const float* __restrict__ q,
    const float* __restrict__ p, float* __restrict__ sc)
{
  __shared__ float red[256];
  const int t = threadIdx.x;
  float s = 0.f;
  for (int i = t; i < 9 * C_IN * C_OUT; i += 256) {
    const float v = w[i];
    s = fmaf(v, v, s);
  }
  red[t] = s;
  __syncthreads();
  for (int off = 128; off > 0; off >>= 1) {
    if (t < off) red[t] += red[t + off];
    __syncthreads();
  }
  if (t == 0) {
    sc[0] = expf(q[0]);
    sc[1] = expf(p[0]);
    sc[2] = sqrtf(red[0]);
  }
}

// ---------------------------------------------------------------------------
// Main: one block per (b, h) output row. 256 threads.
//   thread (wg = t&15, cg = t>>4): 8 consecutive w pixels (wg*8..+7) x
//   8 consecutive c_out (cg*8..+7)  -> 64 fp32 accumulators.
// LDS:
//   xs[64][130]  : x row (h+kh-1), columns stored permuted pi(w)=(w&7)*16+(w>>3)
//                  so stride-8 lane reads hit 16 consecutive banks (no conflict).
//                  slots 128,129 = zero pads for w=-1 / w=128.
//   wsl[3][64][128]: weight slice for current kh (all kw). Reads are 16-lane
//                  broadcast b128 -> conflict-free.
//   Srow[130]    : per-pixel channel sum of squares (patch-norm row), padded.
// ---------------------------------------------------------------------------
__global__ __launch_bounds__(256, 1) void scs_main(
    const float* __restrict__ x, const float* __restrict__ wq,
    const float* __restrict__ bias, const float* __restrict__ sc,
    float* __restrict__ out)
{
  __shared__ float xs[C_IN][130];
  __shared__ float wsl[3][C_IN][C_OUT];
  __shared__ float Srow[130];

  const int t  = threadIdx.x;
  const int bi = blockIdx.x;
  const int b  = bi >> 7;
  const int h  = bi & 127;
  const int wg = t & 15;
  const int cg = t >> 4;
  const int w0 = wg << 3;
  const int co0 = cg << 3;

  // permuted LDS column offsets for u = w0-1 .. w0+8 (10 values)
  int off[10];
#pragma unroll
  for (int j2 = 0; j2 < 10; ++j2) {
    const int u = w0 - 1 + j2;
    off[j2] = (u < 0) ? 128 : ((u > 127) ? 129 : (((u & 7) << 4) + (u >> 3)));
  }

  float acc[8][8];
#pragma unroll
  for (int j = 0; j < 8; ++j)
#pragma unroll
    for (int c = 0; c < 8; ++c) acc[j][c] = 0.f;
  float psum[8];
#pragma unroll
  for (int j = 0; j < 8; ++j) psum[j] = 0.f;

  const float qe = sc[0];
  const float pe = sc[1];
  const float nk = sc[2];

  for (int kh = 0; kh < 3; ++kh) {
    __syncthreads();  // protect LDS from previous iteration's readers
    const int row = h + kh - 1;
    const bool valid = (row >= 0) && (row < H_N);

    // ---- stage x row into permuted LDS layout (float4 global reads) ----
#pragma unroll
    for (int r = 0; r < 8; ++r) {
      const int f4 = (r << 8) + t;          // 0..2047
      const int ci = f4 >> 5;
      const int w4 = (f4 & 31) << 2;        // 0,4,..,124
      float4 v = make_float4(0.f, 0.f, 0.f, 0.f);
      if (valid)
        v = *reinterpret_cast<const float4*>(
            x + (((size_t)b * C_IN + ci) * H_N + row) * W_N + w4);
      xs[ci][(((w4 + 0) & 7) << 4) + ((w4 + 0) >> 3)] = v.x;
      xs[ci][(((w4 + 1) & 7) << 4) + ((w4 + 1) >> 3)] = v.y;
      xs[ci][(((w4 + 2) & 7) << 4) + ((w4 + 2) >> 3)] = v.z;
      xs[ci][(((w4 + 3) & 7) << 4) + ((w4 + 3) >> 3)] = v.w;
    }
    if (t < C_IN) { xs[t][128] = 0.f; xs[t][129] = 0.f; }

    // ---- stage weight slice for this kh: rows (kh*3+kw)*64+ci ----
#pragma unroll
    for (int r = 0; r < 24; ++r) {
      const int f4 = (r << 8) + t;          // 0..6143
      const int kwci = f4 >> 5;             // 0..191
      const int kw = kwci >> 6;
      const int ci = kwci & 63;
      const int c4 = (f4 & 31) << 2;
      *reinterpret_cast<float4*>(&wsl[kw][ci][c4]) =
          *reinterpret_cast<const float4*>(
              wq + (size_t)((kh * 3 + kw) * C_IN + ci) * C_OUT + c4);
    }
    __syncthreads();

    // ---- per-pixel channel sum of squares for this row ----
    if (t < W_N) {
      const int pw = ((t & 7) << 4) + (t >> 3);  // pi(t)
      float s = 0.f;
#pragma unroll 8
      for (int ci = 0; ci < C_IN; ++ci) {
        const float v = xs[ci][pw];
        s = fmaf(v, v, s);
      }
      Srow[t + 1] = s;
    }
    if (t == 0) { Srow[0] = 0.f; Srow[129] = 0.f; }
    __syncthreads();

    // ---- accumulate patch norm (cols w-1,w,w+1 of this row) ----
#pragma unroll
    for (int j = 0; j < 8; ++j)
      psum[j] += Srow[w0 + j] + Srow[w0 + j + 1] + Srow[w0 + j + 2];

    // ---- main FMA loop: 192 FMA per ci, 10 b32 + 6 b128 LDS reads ----
#pragma unroll 2
    for (int ci = 0; ci < C_IN; ++ci) {
      float xr[10];
#pragma unroll
      for (int j2 = 0; j2 < 10; ++j2) xr[j2] = xs[ci][off[j2]];
      float4 wr[3][2];
#pragma unroll
      for (int kw = 0; kw < 3; ++kw) {
        wr[kw][0] = *reinterpret_cast<const float4*>(&wsl[kw][ci][co0]);
        wr[kw][1] = *reinterpret_cast<const float4*>(&wsl[kw][ci][co0 + 4]);
      }
#pragma unroll
      for (int kw = 0; kw < 3; ++kw) {
#pragma unroll
        for (int j = 0; j < 8; ++j) {
          const float xv = xr[j + kw];
          acc[j][0] = fmaf(xv, wr[kw][0].x, acc[j][0]);
          acc[j][1] = fmaf(xv, wr[kw][0].y, acc[j][1]);
          acc[j][2] = fmaf(xv, wr[kw][0].z, acc[j][2]);
          acc[j][3] = fmaf(xv, wr[kw][0].w, acc[j][3]);
          acc[j][4] = fmaf(xv, wr[kw][1].x, acc[j][4]);
          acc[j][5] = fmaf(xv, wr[kw][1].y, acc[j][5]);
          acc[j][6] = fmaf(xv, wr[kw][1].z, acc[j][6]);
          acc[j][7] = fmaf(xv, wr[kw][1].w, acc[j][7]);
        }
      }
    }
  }

  // ---- epilogue: sim = s/((sqrt(psum)+qe)*(nk+qe)); out = sign*|sim|^pe + b
  const float nkq = nk + qe;
  float inv_[8];
#pragma unroll
  for (int j = 0; j < 8; ++j)
    inv_[j] = 1.0f / ((sqrtf(psum[j]) + qe) * nkq);

#pragma unroll
  for (int c = 0; c < 8; ++c) {
    const float bv = bias[co0 + c];
    float o[8];
#pragma unroll
    for (int j = 0; j < 8; ++j) {
      const float s  = acc[j][c];
      const float as = fabsf(s) * inv_[j];           // |sim|
      // |sim|^pe = exp2(pe * log2|sim|); v_log_f32(0) = -inf -> v_exp_f32 = 0
      const float r  = __builtin_amdgcn_exp2f(pe * __builtin_amdgcn_logf(as));
      o[j] = copysignf(r, s) + bv;
    }
    float4* dst = reinterpret_cast<float4*>(
        out + (((size_t)b * C_OUT + co0 + c) * H_N + h) * W_N + w0);
    dst[0] = make_float4(o[0], o[1], o[2], o[3]);
    dst[1] = make_float4(o[4], o[5], o[6], o[7]);
  }
}

// ---------------------------------------------------------------------------
extern "C" void kernel_launch(void* const* d_in, const int* in_sizes, int n_in,
                              void* d_out, int out_size, void* d_ws, size_t ws_size,
                              hipStream_t stream) {
  const float* x = (const float*)d_in[0];
  const float* w = (const float*)d_in[1];
  const float* b = (const float*)d_in[2];
  const float* q = (const float*)d_in[3];
  const float* p = (const float*)d_in[4];
  float* out = (float*)d_out;
  float* sc  = (float*)d_ws;   // [qe, pe, nk]

  scs_prep<<<1, 256, 0, stream>>>(w, q, p, sc);
  scs_main<<<B_N * H_N, 256, 0, stream>>>(x, w, b, sc, out);
}

// Round 4
// 154.218 us; speedup vs baseline: 3.9404x; 3.9404x over previous
//
#include <hip/hip_runtime.h>
#include <math.h>

#define B_N 16
#define C_IN 64
#define H_N 128
#define W_N 128
#define C_OUT 128

typedef __attribute__((ext_vector_type(8))) short short8v;   // 8 bf16 (4 VGPR)
typedef __attribute__((ext_vector_type(4))) float float4v;

__device__ __forceinline__ unsigned short f2bf(float f) {
  union { float f; unsigned u; } c; c.f = f;
  unsigned u = c.u + 0x7fffu + ((c.u >> 16) & 1u);   // RNE
  return (unsigned short)(u >> 16);
}

// ---------------------------------------------------------------------------
// Prep A: scalars qe=exp(q), pe=exp(p), nk=||w||_F into sc[0..2]
// ---------------------------------------------------------------------------
__global__ __launch_bounds__(256) void scs_prep(
    const float* __restrict__ w, const float* __restrict__ q,
    const float* __restrict__ p, float* __restrict__ sc)
{
  __shared__ float red[256];
  const int t = threadIdx.x;
  float s = 0.f;
  for (int i = t; i < 9 * C_IN * C_OUT; i += 256) {
    const float v = w[i];
    s = fmaf(v, v, s);
  }
  red[t] = s;
  __syncthreads();
  for (int off = 128; off > 0; off >>= 1) {
    if (t < off) red[t] += red[t + off];
    __syncthreads();
  }
  if (t == 0) {
    sc[0] = expf(q[0]);
    sc[1] = expf(p[0]);
    sc[2] = sqrtf(red[0]);
  }
}

// ---------------------------------------------------------------------------
// Prep B: pack weights into per-lane B-fragment order (bf16).
// frag id = (kh*6 + s)*8 + nt   (s = K-step of 32 within kh; k' = kw*64+ci)
// lane l supplies B[k = s*32 + (l>>4)*8 + j][n = nt*16 + (l&15)], j=0..7
// stored contiguously: wf[frag*512 + l*8 + j]  -> wave loads 1KB coalesced.
// ---------------------------------------------------------------------------
__global__ __launch_bounds__(256) void scs_prep_w(
    const float* __restrict__ w, unsigned short* __restrict__ wf)
{
  const int gid  = blockIdx.x * 256 + threadIdx.x;  // 0..9215
  const int frag = gid >> 6;                        // 0..143
  const int l    = gid & 63;
  const int kh   = frag / 48;
  const int rem  = frag % 48;
  const int s    = rem >> 3;
  const int nt   = rem & 7;
  const int kb   = kh * 192 + s * 32 + (l >> 4) * 8;
  const int n    = nt * 16 + (l & 15);
  short8v pk;
#pragma unroll
  for (int j = 0; j < 8; ++j)
    pk[j] = (short)f2bf(w[(size_t)(kb + j) * C_OUT + n]);
  *reinterpret_cast<short8v*>(wf + (size_t)frag * 512 + l * 8) = pk;
}

// ---------------------------------------------------------------------------
// Main: block = (b,h). 512 threads = 8 waves (2 in M x 4 in N).
// M = 128 w-pixels (8 tiles of 16), N = 128 c_out (8 tiles), K = 576.
// x row staged as bf16 xT[w+1][ci] (swizzled, pad rows 0/129 = zeros);
// A-frag = 1 ds_read_b128; B-frag = global dwordx4 from prepped wf (L2).
// Patch norms: fp32 squares accumulated during staging -> psacc4 -> Stot.
// ---------------------------------------------------------------------------
__global__ __launch_bounds__(512, 4) void scs_main(
    const float* __restrict__ x, const unsigned short* __restrict__ wf,
    const float* __restrict__ bias, const float* __restrict__ sc,
    float* __restrict__ out)
{
  __shared__ alignas(16) char xT[130 * 128];   // bf16 [j=w+1][ci], 128B rows, XOR-swizzled
  __shared__ float psacc4[4][128];
  __shared__ float Stot[130];

  const int t   = threadIdx.x;
  const int l   = t & 63;
  const int wid = t >> 6;
  const int wm  = wid >> 2;        // 0..1  (M)
  const int wn  = wid & 3;         // 0..3  (N)
  const int lr  = l & 15;
  const int lg  = l >> 4;
  const int b   = blockIdx.x >> 7;
  const int h   = blockIdx.x & 127;

  const float qe = sc[0], pe = sc[1], nk = sc[2];

  // init: zero pad rows (j=0, j=129) and psacc4
  if (t < 16) {
    const int j   = (t < 8) ? 0 : 129;
    const int off = (t & 7) * 16;
    *reinterpret_cast<float4v*>(xT + j * 128 + off) = float4v{0.f, 0.f, 0.f, 0.f};
  }
  psacc4[t >> 7][t & 127] = 0.f;

  float4v acc[4][2];
#pragma unroll
  for (int ml = 0; ml < 4; ++ml)
#pragma unroll
    for (int nl = 0; nl < 2; ++nl) acc[ml][nl] = float4v{0.f, 0.f, 0.f, 0.f};

  for (int kh = 0; kh < 3; ++kh) {
    __syncthreads();                       // previous tile's readers done
    const int  row   = h + kh - 1;
    const bool valid = (row >= 0) && (row < H_N);
    const int  rsafe = valid ? row : 0;
    float part = 0.f;

    // ---- stage x row -> bf16 xT (transposed, swizzled); fp32 squares ----
#pragma unroll
    for (int r = 0; r < 2; ++r) {
      const int idx = r * 512 + t;         // 0..1023
      const int cc  = idx >> 7;            // ci chunk (8 ci)
      const int w   = idx & 127;
      const float* src = x + (((size_t)b * C_IN + cc * 8) * H_N + rsafe) * W_N + w;
      float xv[8];
#pragma unroll
      for (int j = 0; j < 8; ++j)
        xv[j] = valid ? src[(size_t)j * H_N * W_N] : 0.f;
#pragma unroll
      for (int j = 0; j < 8; ++j) part = fmaf(xv[j], xv[j], part);
      union { unsigned u[4]; short8v v; } pk;
#pragma unroll
      for (int j = 0; j < 4; ++j)
        pk.u[j] = (unsigned)f2bf(xv[2 * j]) | ((unsigned)f2bf(xv[2 * j + 1]) << 16);
      const int jr = w + 1;
      int byte = jr * 128 + cc * 16;
      byte ^= (jr & 7) << 4;
      *reinterpret_cast<short8v*>(xT + byte) = pk.v;
    }
    psacc4[t >> 7][t & 127] += part;       // unique writer per cell
    __syncthreads();                       // tile ready

    // ---- MFMA: 6 K-steps of 32 (kw = s>>1, ci half = s&1) ----
#pragma unroll
    for (int s = 0; s < 6; ++s) {
      const int kw  = s >> 1;
      const int ci0 = (s & 1) * 32 + lg * 8;
      short8v a[4];
#pragma unroll
      for (int ml = 0; ml < 4; ++ml) {
        const int jr = (wm * 4 + ml) * 16 + lr + kw;   // = w + 1 (w = tile row + kw-1)
        int byte = jr * 128 + ci0 * 2;
        byte ^= (jr & 7) << 4;
        a[ml] = *reinterpret_cast<const short8v*>(xT + byte);
      }
      short8v bf[2];
#pragma unroll
      for (int nl = 0; nl < 2; ++nl) {
        const int fi = (kh * 6 + s) * 8 + (wn * 2 + nl);
        bf[nl] = *reinterpret_cast<const short8v*>(wf + (size_t)fi * 512 + l * 8);
      }
#pragma unroll
      for (int ml = 0; ml < 4; ++ml)
#pragma unroll
        for (int nl = 0; nl < 2; ++nl)
          acc[ml][nl] = __builtin_amdgcn_mfma_f32_16x16x32_bf16(
              a[ml], bf[nl], acc[ml][nl], 0, 0, 0);
    }
  }

  // ---- reduce patch-norm partials ----
  if (t < 128)       Stot[t + 1] = psacc4[0][t] + psacc4[1][t] + psacc4[2][t] + psacc4[3][t];
  else if (t == 128) Stot[0]   = 0.f;
  else if (t == 129) Stot[129] = 0.f;
  __syncthreads();

  // ---- epilogue ----
  const float nkq = nk + qe;
  float inv_[4][4];
#pragma unroll
  for (int ml = 0; ml < 4; ++ml) {
    const int w0 = (wm * 4 + ml) * 16 + lg * 4;
#pragma unroll
    for (int r = 0; r < 4; ++r) {
      const float P = Stot[w0 + r] + Stot[w0 + r + 1] + Stot[w0 + r + 2];
      inv_[ml][r] = 1.f / ((sqrtf(P) + qe) * nkq);
    }
  }
#pragma unroll
  for (int nl = 0; nl < 2; ++nl) {
    const int n  = (wn * 2 + nl) * 16 + lr;
    const float bv = bias[n];
#pragma unroll
    for (int ml = 0; ml < 4; ++ml) {
      const int w0 = (wm * 4 + ml) * 16 + lg * 4;
      float4v o;
#pragma unroll
      for (int r = 0; r < 4; ++r) {
        const float sv = acc[ml][nl][r];
        const float as = fabsf(sv) * inv_[ml][r];
        const float rr = __builtin_amdgcn_exp2f(pe * __builtin_amdgcn_logf(as));
        o[r] = copysignf(rr, sv) + bv;
      }
      *reinterpret_cast<float4v*>(
          out + (((size_t)b * C_OUT + n) * H_N + h) * W_N + w0) = o;
    }
  }
}

// ---------------------------------------------------------------------------
extern "C" void kernel_launch(void* const* d_in, const int* in_sizes, int n_in,
                              void* d_out, int out_size, void* d_ws, size_t ws_size,
                              hipStream_t stream) {
  const float* x = (const float*)d_in[0];
  const float* w = (const float*)d_in[1];
  const float* b = (const float*)d_in[2];
  const float* q = (const float*)d_in[3];
  const float* p = (const float*)d_in[4];
  float* out = (float*)d_out;
  float* sc  = (float*)d_ws;                                   // [qe, pe, nk]
  unsigned short* wf = (unsigned short*)((char*)d_ws + 256);   // 144KB B-frags

  scs_prep<<<1, 256, 0, stream>>>(w, q, p, sc);
  scs_prep_w<<<36, 256, 0, stream>>>(w, wf);
  scs_main<<<B_N * H_N, 512, 0, stream>>>(x, wf, b, sc, out);
}

// Round 7
// 79.375 us; speedup vs baseline: 7.6558x; 1.9429x over previous
//
#include <hip/hip_runtime.h>
#include <math.h>

#define B_N 16
#define C_IN 64
#define H_N 128
#define W_N 128
#define C_OUT 128

typedef __attribute__((ext_vector_type(8))) short short8v;   // 8 bf16 (4 VGPR)
typedef __attribute__((ext_vector_type(4))) float float4v;

__device__ __forceinline__ unsigned short f2bf(float f) {
  union { float f; unsigned u; } c; c.f = f;
  unsigned u = c.u + 0x7fffu + ((c.u >> 16) & 1u);   // RNE
  return (unsigned short)(u >> 16);
}

// ---------------------------------------------------------------------------
// Prep: pack weights into per-lane B-fragment order (bf16) AND compute
// per-block partial sums of w^2 (each element is read exactly once across
// the grid, so sum(partial) = ||w||_F^2, deterministically).
// frag id = (kh*6 + s)*8 + nt   (s = K-step of 32 within kh; k' = kw*64+ci)
// lane l supplies B[k = s*32 + (l>>4)*8 + j][n = nt*16 + (l&15)], j=0..7
// stored contiguously: wf[frag*512 + l*8 + j]  -> wave loads 1KB coalesced.
// ---------------------------------------------------------------------------
__global__ __launch_bounds__(256) void scs_prep_w(
    const float* __restrict__ w, unsigned short* __restrict__ wf,
    float* __restrict__ partial)
{
  __shared__ float red[256];
  const int t    = threadIdx.x;
  const int gid  = blockIdx.x * 256 + t;            // 0..9215
  const int frag = gid >> 6;                        // 0..143
  const int l    = gid & 63;
  const int kh   = frag / 48;
  const int rem  = frag % 48;
  const int s    = rem >> 3;
  const int nt   = rem & 7;
  const int kb   = kh * 192 + s * 32 + (l >> 4) * 8;
  const int n    = nt * 16 + (l & 15);
  short8v pk;
  float ss = 0.f;
#pragma unroll
  for (int j = 0; j < 8; ++j) {
    const float v = w[(size_t)(kb + j) * C_OUT + n];
    ss = fmaf(v, v, ss);
    pk[j] = (short)f2bf(v);
  }
  *reinterpret_cast<short8v*>(wf + (size_t)frag * 512 + l * 8) = pk;
  red[t] = ss;
  __syncthreads();
  for (int off = 128; off > 0; off >>= 1) {
    if (t < off) red[t] += red[t + off];
    __syncthreads();
  }
  if (t == 0) partial[blockIdx.x] = red[0];
}

// ---------------------------------------------------------------------------
// Main: block = (b,h). 512 threads = 8 waves (2 in M x 4 in N).
// M = 128 w-pixels (8 tiles of 16), N = 128 c_out (8 tiles), K = 576.
// x row staged as bf16 xT[w+1][ci] (swizzled, pad rows 0/129 = zeros);
// A-frag = 1 ds_read_b128; B-frag = global dwordx4 from prepped wf (L2).
// Patch norms: fp32 squares accumulated during staging -> psacc4 -> Stot.
// XCD-aware block swizzle (2048 % 8 == 0 -> bijective): each XCD gets a
// contiguous (b,h) chunk so neighboring h (sharing 2 of 3 x rows) hit L2.
// ---------------------------------------------------------------------------
__global__ __launch_bounds__(512, 4) void scs_main(
    const float* __restrict__ x, const unsigned short* __restrict__ wf,
    const float* __restrict__ bias, const float* __restrict__ q,
    const float* __restrict__ p, const float* __restrict__ partial,
    float* __restrict__ out)
{
  __shared__ alignas(16) char xT[130 * 128];   // bf16 [j=w+1][ci], 128B rows, XOR-swizzled
  __shared__ float psacc4[4][128];
  __shared__ float Stot[130];

  const int t   = threadIdx.x;
  const int l   = t & 63;
  const int wid = t >> 6;
  const int wm  = wid >> 2;        // 0..1  (M)
  const int wn  = wid & 3;         // 0..3  (N)
  const int lr  = l & 15;
  const int lg  = l >> 4;
  const int bid = blockIdx.x;
  const int swz = (bid & 7) * 256 + (bid >> 3);   // XCD-contiguous remap
  const int b   = swz >> 7;
  const int h   = swz & 127;

  // scalars: qe, pe, nk (all loads L1/L2-cached, redundant per thread)
  float ssum = 0.f;
#pragma unroll
  for (int i = 0; i < 36; ++i) ssum += partial[i];
  const float nk = sqrtf(ssum);
  const float qe = expf(q[0]);
  const float pe = expf(p[0]);

  // init: zero pad rows (j=0, j=129) and psacc4
  if (t < 16) {
    const int j   = (t < 8) ? 0 : 129;
    const int off = (t & 7) * 16;
    *reinterpret_cast<float4v*>(xT + j * 128 + off) = float4v{0.f, 0.f, 0.f, 0.f};
  }
  psacc4[t >> 7][t & 127] = 0.f;

  float4v acc[4][2];
#pragma unroll
  for (int ml = 0; ml < 4; ++ml)
#pragma unroll
    for (int nl = 0; nl < 2; ++nl) acc[ml][nl] = float4v{0.f, 0.f, 0.f, 0.f};

  for (int kh = 0; kh < 3; ++kh) {
    __syncthreads();                       // previous tile's readers done
    const int  row   = h + kh - 1;
    const bool valid = (row >= 0) && (row < H_N);
    const int  rsafe = valid ? row : 0;
    float part = 0.f;

    // ---- stage x row -> bf16 xT (transposed, swizzled); fp32 squares ----
#pragma unroll
    for (int r = 0; r < 2; ++r) {
      const int idx = r * 512 + t;         // 0..1023
      const int cc  = idx >> 7;            // ci chunk (8 ci)
      const int w   = idx & 127;
      const float* src = x + (((size_t)b * C_IN + cc * 8) * H_N + rsafe) * W_N + w;
      float xv[8];
#pragma unroll
      for (int j = 0; j < 8; ++j)
        xv[j] = valid ? src[(size_t)j * H_N * W_N] : 0.f;
#pragma unroll
      for (int j = 0; j < 8; ++j) part = fmaf(xv[j], xv[j], part);
      union { unsigned u[4]; short8v v; } pk;
#pragma unroll
      for (int j = 0; j < 4; ++j)
        pk.u[j] = (unsigned)f2bf(xv[2 * j]) | ((unsigned)f2bf(xv[2 * j + 1]) << 16);
      const int jr = w + 1;
      int byte = jr * 128 + cc * 16;
      byte ^= (jr & 7) << 4;
      *reinterpret_cast<short8v*>(xT + byte) = pk.v;
    }
    psacc4[t >> 7][t & 127] += part;       // unique writer per cell
    __syncthreads();                       // tile ready

    // ---- MFMA: 6 K-steps of 32 (kw = s>>1, ci half = s&1) ----
#pragma unroll
    for (int s = 0; s < 6; ++s) {
      const int kw  = s >> 1;
      const int ci0 = (s & 1) * 32 + lg * 8;
      short8v a[4];
#pragma unroll
      for (int ml = 0; ml < 4; ++ml) {
        const int jr = (wm * 4 + ml) * 16 + lr + kw;   // = w + 1 (w = tile row + kw-1)
        int byte = jr * 128 + ci0 * 2;
        byte ^= (jr & 7) << 4;
        a[ml] = *reinterpret_cast<const short8v*>(xT + byte);
      }
      short8v bf[2];
#pragma unroll
      for (int nl = 0; nl < 2; ++nl) {
        const int fi = (kh * 6 + s) * 8 + (wn * 2 + nl);
        bf[nl] = *reinterpret_cast<const short8v*>(wf + (size_t)fi * 512 + l * 8);
      }
#pragma unroll
      for (int ml = 0; ml < 4; ++ml)
#pragma unroll
        for (int nl = 0; nl < 2; ++nl)
          acc[ml][nl] = __builtin_amdgcn_mfma_f32_16x16x32_bf16(
              a[ml], bf[nl], acc[ml][nl], 0, 0, 0);
    }
  }

  // ---- reduce patch-norm partials ----
  if (t < 128)       Stot[t + 1] = psacc4[0][t] + psacc4[1][t] + psacc4[2][t] + psacc4[3][t];
  else if (t == 128) Stot[0]   = 0.f;
  else if (t == 129) Stot[129] = 0.f;
  __syncthreads();

  // ---- epilogue ----
  const float nkq = nk + qe;
  float inv_[4][4];
#pragma unroll
  for (int ml = 0; ml < 4; ++ml) {
    const int w0 = (wm * 4 + ml) * 16 + lg * 4;
#pragma unroll
    for (int r = 0; r < 4; ++r) {
      const float P = Stot[w0 + r] + Stot[w0 + r + 1] + Stot[w0 + r + 2];
      inv_[ml][r] = 1.f / ((sqrtf(P) + qe) * nkq);
    }
  }
#pragma unroll
  for (int nl = 0; nl < 2; ++nl) {
    const int n  = (wn * 2 + nl) * 16 + lr;
    const float bv = bias[n];
#pragma unroll
    for (int ml = 0; ml < 4; ++ml) {
      const int w0 = (wm * 4 + ml) * 16 + lg * 4;
      float4v o;
#pragma unroll
      for (int r = 0; r < 4; ++r) {
        const float sv = acc[ml][nl][r];
        const float as = fabsf(sv) * inv_[ml][r];
        const float rr = __builtin_amdgcn_exp2f(pe * __builtin_amdgcn_logf(as));
        o[r] = copysignf(rr, sv) + bv;
      }
      *reinterpret_cast<float4v*>(
          out + (((size_t)b * C_OUT + n) * H_N + h) * W_N + w0) = o;
    }
  }
}

// ---------------------------------------------------------------------------
extern "C" void kernel_launch(void* const* d_in, const int* in_sizes, int n_in,
                              void* d_out, int out_size, void* d_ws, size_t ws_size,
                              hipStream_t stream) {
  const float* x = (const float*)d_in[0];
  const float* w = (const float*)d_in[1];
  const float* b = (const float*)d_in[2];
  const float* q = (const float*)d_in[3];
  const float* p = (const float*)d_in[4];
  float* out = (float*)d_out;
  float* partial = (float*)d_ws;                               // 36 floats
  unsigned short* wf = (unsigned short*)((char*)d_ws + 256);   // 144KB B-frags

  scs_prep_w<<<36, 256, 0, stream>>>(w, wf, partial);
  scs_main<<<B_N * H_N, 512, 0, stream>>>(x, wf, b, q, p, partial, out);
}

// Round 8
// 65.245 us; speedup vs baseline: 9.3138x; 1.2166x over previous
//
#include <hip/hip_runtime.h>
#include <math.h>

#define B_N 16
#define C_IN 64
#define H_N 128
#define W_N 128
#define C_OUT 128

typedef __attribute__((ext_vector_type(8))) short short8v;   // 8 bf16 (4 VGPR)
typedef __attribute__((ext_vector_type(4))) float float4v;

__device__ __forceinline__ unsigned short f2bf(float f) {
  union { float f; unsigned u; } c; c.f = f;
  unsigned u = c.u + 0x7fffu + ((c.u >> 16) & 1u);   // RNE
  return (unsigned short)(u >> 16);
}

// ---------------------------------------------------------------------------
// Prep: pack weights into per-lane B-fragment order (bf16) AND per-block
// partial sums of w^2 (each element read exactly once -> deterministic).
// frag id = (kh*6 + s)*8 + nt ; lane l supplies B[k=s*32+(l>>4)*8+j][n=nt*16+(l&15)]
// ---------------------------------------------------------------------------
__global__ __launch_bounds__(256) void scs_prep_w(
    const float* __restrict__ w, unsigned short* __restrict__ wf,
    float* __restrict__ partial)
{
  __shared__ float red[256];
  const int t    = threadIdx.x;
  const int gid  = blockIdx.x * 256 + t;            // 0..9215
  const int frag = gid >> 6;                        // 0..143
  const int l    = gid & 63;
  const int kh   = frag / 48;
  const int rem  = frag % 48;
  const int s    = rem >> 3;
  const int nt   = rem & 7;
  const int kb   = kh * 192 + s * 32 + (l >> 4) * 8;
  const int n    = nt * 16 + (l & 15);
  short8v pk;
  float ss = 0.f;
#pragma unroll
  for (int j = 0; j < 8; ++j) {
    const float v = w[(size_t)(kb + j) * C_OUT + n];
    ss = fmaf(v, v, ss);
    pk[j] = (short)f2bf(v);
  }
  *reinterpret_cast<short8v*>(wf + (size_t)frag * 512 + l * 8) = pk;
  red[t] = ss;
  __syncthreads();
  for (int off = 128; off > 0; off >>= 1) {
    if (t < off) red[t] += red[t + off];
    __syncthreads();
  }
  if (t == 0) partial[blockIdx.x] = red[0];
}

// ---------------------------------------------------------------------------
// Main v3: block = (b, pair of output rows h0,h0+1). 1024 blocks, 512 thr.
// Stages 4 input rows (h0-1..h0+2) ONCE as bf16 xT[4][130][64] (XOR-swizzled),
// then one barrier-free MFMA loop: per K-step s=(kw,cihalf), rolling over the
// 4 input rows; A-frags shared between the 2 output rows, B-frags loaded once.
// Patch norms: per-row channel sums (Ss) -> 3-col sums (csum) -> epilogue.
// ---------------------------------------------------------------------------
__global__ __launch_bounds__(512, 4) void scs_main(
    const float* __restrict__ x, const unsigned short* __restrict__ wf,
    const float* __restrict__ bias, const float* __restrict__ q,
    const float* __restrict__ p, const float* __restrict__ partial,
    float* __restrict__ out)
{
  __shared__ alignas(16) char xT[4 * 16640];   // 4 rows x 130 slots x 128B
  __shared__ float psacc[4][4][128];
  __shared__ float Ss[4][130];
  __shared__ float csum[4][128];

  const int t   = threadIdx.x;
  const int l   = t & 63;
  const int wid = t >> 6;
  const int wm  = wid >> 2;        // 0..1  (M half: 64 pixels)
  const int wn  = wid & 3;         // 0..3  (N quarter: 32 couts)
  const int lr  = l & 15;
  const int lg  = l >> 4;
  const int bid = blockIdx.x;
  const int swz = (bid & 7) * 128 + (bid >> 3);   // bijective XCD remap (1024%8==0)
  const int b   = swz >> 6;
  const int h0  = (swz & 63) << 1;

  // scalars (cheap, cached): nk, qe, pe
  float ssum = 0.f;
#pragma unroll
  for (int i = 0; i < 36; ++i) ssum += partial[i];
  const float nk = sqrtf(ssum);
  const float qe = __builtin_amdgcn_exp2f(q[0] * 1.4426950408889634f);
  const float pe = __builtin_amdgcn_exp2f(p[0] * 1.4426950408889634f);

  // zero the w-pad slots (jr=0 and jr=129) of all 4 rows
  if (t < 64) {
    const int k   = t >> 3;                 // 0..7
    const int row = k >> 1;
    const int jr  = (k & 1) ? 129 : 0;
    *reinterpret_cast<float4v*>(xT + row * 16640 + jr * 128 + (t & 7) * 16) =
        float4v{0.f, 0.f, 0.f, 0.f};
  }

  // ---- stage 4 input rows -> bf16 xT (transposed, swizzled); fp32 squares --
  const int wcol  = t & 127;
  const int cbase = t >> 7;                 // 0..3
  float part0 = 0.f, part1 = 0.f, part2 = 0.f, part3 = 0.f;
#pragma unroll
  for (int it = 0; it < 8; ++it) {
    const int  row4  = it >> 1;             // compile-time
    const int  cc    = (it & 1) * 4 + cbase;
    const int  inr   = h0 - 1 + row4;
    const bool valid = (unsigned)inr < 128u;
    const float* src = x + (((size_t)b * C_IN + cc * 8) * H_N + (valid ? inr : 0)) * W_N + wcol;
    float xv[8];
#pragma unroll
    for (int j = 0; j < 8; ++j)
      xv[j] = valid ? src[(size_t)j * H_N * W_N] : 0.f;
    float pp = 0.f;
#pragma unroll
    for (int j = 0; j < 8; ++j) pp = fmaf(xv[j], xv[j], pp);
    if      (row4 == 0) part0 += pp;
    else if (row4 == 1) part1 += pp;
    else if (row4 == 2) part2 += pp;
    else                part3 += pp;
    union { unsigned u[4]; short8v v; } pk;
#pragma unroll
    for (int j = 0; j < 4; ++j)
      pk.u[j] = (unsigned)f2bf(xv[2 * j]) | ((unsigned)f2bf(xv[2 * j + 1]) << 16);
    const int jr = wcol + 1;
    int byte = row4 * 16640 + jr * 128 + cc * 16;
    byte ^= (jr & 7) << 4;
    *reinterpret_cast<short8v*>(xT + byte) = pk.v;
  }
  psacc[cbase][0][wcol] = part0;
  psacc[cbase][1][wcol] = part1;
  psacc[cbase][2][wcol] = part2;
  psacc[cbase][3][wcol] = part3;
  __syncthreads();

  // ---- per-row channel sums, then 3-col sums -------------------------------
  {
    const int rr = t >> 7, w = t & 127;
    Ss[rr][w + 1] = psacc[0][rr][w] + psacc[1][rr][w] + psacc[2][rr][w] + psacc[3][rr][w];
    if (w == 0)   Ss[rr][0]   = 0.f;
    if (w == 127) Ss[rr][129] = 0.f;
  }
  __syncthreads();
  {
    const int rr = t >> 7, w = t & 127;
    csum[rr][w] = Ss[rr][w] + Ss[rr][w + 1] + Ss[rr][w + 2];
  }
  __syncthreads();

  // ---- MFMA: 6 K-steps of 32, rolling over 4 input rows -------------------
  float4v acc[2][4][2];
#pragma unroll
  for (int o = 0; o < 2; ++o)
#pragma unroll
    for (int ml = 0; ml < 4; ++ml)
#pragma unroll
      for (int nl = 0; nl < 2; ++nl) acc[o][ml][nl] = float4v{0.f, 0.f, 0.f, 0.f};

  const int jbase = wm * 64 + lr;
#pragma unroll
  for (int s = 0; s < 6; ++s) {
    const int kw    = s >> 1;
    const int half  = s & 1;
    const int cslot = half * 4 + lg;
    const int jlow  = (lr + kw) & 7;
    const int base_s = (jbase + kw) * 128 + ((cslot * 16) ^ (jlow << 4));
    short8v bfr[3][2];
#pragma unroll
    for (int r = 0; r < 4; ++r) {
      short8v a[4];
#pragma unroll
      for (int ml = 0; ml < 4; ++ml)
        a[ml] = *reinterpret_cast<const short8v*>(xT + base_s + r * 16640 + ml * 2048);
      if (r < 3) {   // load B-frags for kh=r (serve o=0 now, o=1 at r+1)
        const int fi = (r * 6 + s) * 8 + wn * 2;
        bfr[r][0] = *reinterpret_cast<const short8v*>(wf + (size_t)(fi + 0) * 512 + l * 8);
        bfr[r][1] = *reinterpret_cast<const short8v*>(wf + (size_t)(fi + 1) * 512 + l * 8);
#pragma unroll
        for (int ml = 0; ml < 4; ++ml)
#pragma unroll
          for (int nl = 0; nl < 2; ++nl)
            acc[0][ml][nl] = __builtin_amdgcn_mfma_f32_16x16x32_bf16(
                a[ml], bfr[r][nl], acc[0][ml][nl], 0, 0, 0);
      }
      if (r >= 1) {  // o=1, kh=r-1
#pragma unroll
        for (int ml = 0; ml < 4; ++ml)
#pragma unroll
          for (int nl = 0; nl < 2; ++nl)
            acc[1][ml][nl] = __builtin_amdgcn_mfma_f32_16x16x32_bf16(
                a[ml], bfr[r - 1][nl], acc[1][ml][nl], 0, 0, 0);
      }
    }
  }

  // ---- epilogue ------------------------------------------------------------
  const float nkq = nk + qe;
#pragma unroll
  for (int o = 0; o < 2; ++o) {
    const int oh = h0 + o;
#pragma unroll
    for (int ml = 0; ml < 4; ++ml) {
      const int w0 = wm * 64 + ml * 16 + lg * 4;
      float inv_[4];
#pragma unroll
      for (int r = 0; r < 4; ++r) {
        const float P = csum[o][w0 + r] + csum[o + 1][w0 + r] + csum[o + 2][w0 + r];
        inv_[r] = 1.f / ((sqrtf(P) + qe) * nkq);
      }
#pragma unroll
      for (int nl = 0; nl < 2; ++nl) {
        const int n  = wn * 32 + nl * 16 + lr;
        const float bv = bias[n];
        float4v ov;
#pragma unroll
        for (int r = 0; r < 4; ++r) {
          const float sv  = acc[o][ml][nl][r];
          const float as  = fabsf(sv) * inv_[r];
          const float rr2 = __builtin_amdgcn_exp2f(pe * __builtin_amdgcn_logf(as));
          ov[r] = copysignf(rr2, sv) + bv;
        }
        *reinterpret_cast<float4v*>(
            out + (((size_t)b * C_OUT + n) * H_N + oh) * W_N + w0) = ov;
      }
    }
  }
}

// ---------------------------------------------------------------------------
extern "C" void kernel_launch(void* const* d_in, const int* in_sizes, int n_in,
                              void* d_out, int out_size, void* d_ws, size_t ws_size,
                              hipStream_t stream) {
  const float* x = (const float*)d_in[0];
  const float* w = (const float*)d_in[1];
  const float* b = (const float*)d_in[2];
  const float* q = (const float*)d_in[3];
  const float* p = (const float*)d_in[4];
  float* out = (float*)d_out;
  float* partial = (float*)d_ws;                               // 36 floats
  unsigned short* wf = (unsigned short*)((char*)d_ws + 256);   // 144KB B-frags

  scs_prep_w<<<36, 256, 0, stream>>>(w, wf, partial);
  scs_main<<<B_N * (H_N / 2), 512, 0, stream>>>(x, wf, b, q, p, partial, out);
}

// Round 9
// 59.224 us; speedup vs baseline: 10.2608x; 1.1017x over previous
//
#include <hip/hip_runtime.h>
#include <hip/hip_bf16.h>
#include <math.h>

#define B_N 16
#define C_IN 64
#define H_N 128
#define W_N 128
#define C_OUT 128

typedef __attribute__((ext_vector_type(8))) short short8v;   // 8 bf16 (4 VGPR)
typedef __attribute__((ext_vector_type(4))) float float4v;

__device__ __forceinline__ unsigned short f2bf(float f) {
  union { float f; unsigned u; } c; c.f = f;
  unsigned u = c.u + 0x7fffu + ((c.u >> 16) & 1u);   // RNE
  return (unsigned short)(u >> 16);
}

// ---------------------------------------------------------------------------
// Prep: pack weights into per-lane B-fragment order (bf16) AND per-block
// partial sums of w^2 (each element read exactly once -> deterministic).
// frag id = (kh*6 + s)*8 + nt ; lane l supplies B[k=s*32+(l>>4)*8+j][n=nt*16+(l&15)]
// ---------------------------------------------------------------------------
__global__ __launch_bounds__(256) void scs_prep_w(
    const float* __restrict__ w, unsigned short* __restrict__ wf,
    float* __restrict__ partial)
{
  __shared__ float red[256];
  const int t    = threadIdx.x;
  const int gid  = blockIdx.x * 256 + t;            // 0..9215
  const int frag = gid >> 6;                        // 0..143
  const int l    = gid & 63;
  const int kh   = frag / 48;
  const int rem  = frag % 48;
  const int s    = rem >> 3;
  const int nt   = rem & 7;
  const int kb   = kh * 192 + s * 32 + (l >> 4) * 8;
  const int n    = nt * 16 + (l & 15);
  short8v pk;
  float ss = 0.f;
#pragma unroll
  for (int j = 0; j < 8; ++j) {
    const float v = w[(size_t)(kb + j) * C_OUT + n];
    ss = fmaf(v, v, ss);
    pk[j] = (short)f2bf(v);
  }
  *reinterpret_cast<short8v*>(wf + (size_t)frag * 512 + l * 8) = pk;
  red[t] = ss;
  __syncthreads();
  for (int off = 128; off > 0; off >>= 1) {
    if (t < off) red[t] += red[t + off];
    __syncthreads();
  }
  if (t == 0) partial[blockIdx.x] = red[0];
}

// ---------------------------------------------------------------------------
// Main v4: block = (b, output rows h0,h0+1). 1024 blocks, 512 threads.
// Stages 4 input rows ONCE as bf16 xT (XOR-swizzled); rolling MFMA loop
// shares A-frags between the 2 output rows; B-frags once per (s,kh).
// Epilogue: per-PIXEL pl = -pe*(log2(sqrt(P)+qe)+log2(nk+qe)) in LDS;
// per-output = exp2(fma(pe, log2|s|, pl)) -> ~5 VALU ops.
// Staging converts via __float22bfloat162_rn (v_cvt_pk_bf16_f32).
// ---------------------------------------------------------------------------
__global__ __launch_bounds__(512, 4) void scs_main(
    const float* __restrict__ x, const unsigned short* __restrict__ wf,
    const float* __restrict__ bias, const float* __restrict__ q,
    const float* __restrict__ p, const float* __restrict__ partial,
    float* __restrict__ out)
{
  __shared__ alignas(16) char xT[4 * 16640];   // 4 rows x 130 slots x 128B
  __shared__ float psacc[4][4][128];           // 8KB
  __shared__ float Ss[4][130];                 // 2.08KB
  __shared__ float pl[2][128];                 // 1KB  (total 77.9KB -> 2 blk/CU)

  const int t   = threadIdx.x;
  const int l   = t & 63;
  const int wid = t >> 6;
  const int wm  = wid >> 2;        // 0..1  (M half: 64 pixels)
  const int wn  = wid & 3;         // 0..3  (N quarter: 32 couts)
  const int lr  = l & 15;
  const int lg  = l >> 4;
  const int bid = blockIdx.x;
  const int swz = (bid & 7) * 128 + (bid >> 3);   // bijective XCD remap (1024%8==0)
  const int b   = swz >> 6;
  const int h0  = (swz & 63) << 1;

  // scalars (cheap, cached): nk, qe, pe
  float ssum = 0.f;
#pragma unroll
  for (int i = 0; i < 36; ++i) ssum += partial[i];
  const float nk = sqrtf(ssum);
  const float qe = __builtin_amdgcn_exp2f(q[0] * 1.4426950408889634f);
  const float pe = __builtin_amdgcn_exp2f(p[0] * 1.4426950408889634f);
  const float nlg_nkq = -__builtin_amdgcn_logf(nk + qe);   // -log2(nk+qe)

  // zero the w-pad slots (jr=0 and jr=129) of all 4 rows
  if (t < 64) {
    const int k   = t >> 3;                 // 0..7
    const int row = k >> 1;
    const int jr  = (k & 1) ? 129 : 0;
    *reinterpret_cast<float4v*>(xT + row * 16640 + jr * 128 + (t & 7) * 16) =
        float4v{0.f, 0.f, 0.f, 0.f};
  }

  // ---- stage 4 input rows -> bf16 xT (transposed, swizzled); fp32 squares --
  const int wcol  = t & 127;
  const int cbase = t >> 7;                 // 0..3
  float part0 = 0.f, part1 = 0.f, part2 = 0.f, part3 = 0.f;
#pragma unroll
  for (int it = 0; it < 8; ++it) {
    const int  row4  = it >> 1;             // compile-time
    const int  cc    = (it & 1) * 4 + cbase;
    const int  inr   = h0 - 1 + row4;
    const bool valid = (unsigned)inr < 128u;   // block-uniform per iteration
    const int  jr    = wcol + 1;
    int byte = row4 * 16640 + jr * 128 + cc * 16;
    byte ^= (jr & 7) << 4;
    if (valid) {
      const float* src = x + (((size_t)b * C_IN + cc * 8) * H_N + inr) * W_N + wcol;
      float xv[8];
#pragma unroll
      for (int j = 0; j < 8; ++j)
        xv[j] = src[(size_t)j * H_N * W_N];
      float pp = 0.f;
#pragma unroll
      for (int j = 0; j < 8; ++j) pp = fmaf(xv[j], xv[j], pp);
      if      (row4 == 0) part0 += pp;
      else if (row4 == 1) part1 += pp;
      else if (row4 == 2) part2 += pp;
      else                part3 += pp;
      union { __hip_bfloat162 h2[4]; short8v v; } pk;
#pragma unroll
      for (int j = 0; j < 4; ++j)
        pk.h2[j] = __float22bfloat162_rn(make_float2(xv[2 * j], xv[2 * j + 1]));
      *reinterpret_cast<short8v*>(xT + byte) = pk.v;
    } else {
      *reinterpret_cast<short8v*>(xT + byte) = short8v{0,0,0,0,0,0,0,0};
    }
  }
  psacc[cbase][0][wcol] = part0;
  psacc[cbase][1][wcol] = part1;
  psacc[cbase][2][wcol] = part2;
  psacc[cbase][3][wcol] = part3;
  __syncthreads();

  // ---- per-row channel sums --------------------------------------------
  {
    const int rr = t >> 7, w = t & 127;
    Ss[rr][w + 1] = psacc[0][rr][w] + psacc[1][rr][w] + psacc[2][rr][w] + psacc[3][rr][w];
    if (w == 0)   Ss[rr][0]   = 0.f;
    if (w == 127) Ss[rr][129] = 0.f;
  }
  __syncthreads();

  // ---- per-pixel epilogue scale: pl = pe*(-log2(sqrt(P)+qe) - log2(nkq)) --
  if (t < 256) {
    const int o = t >> 7;        // 0..1
    const int w = t & 127;
    float P = 0.f;
#pragma unroll
    for (int r = 0; r < 3; ++r)
      P += Ss[o + r][w] + Ss[o + r][w + 1] + Ss[o + r][w + 2];
    pl[o][w] = pe * (nlg_nkq - __builtin_amdgcn_logf(sqrtf(P) + qe));
  }
  __syncthreads();

  // ---- MFMA: 6 K-steps of 32, rolling over 4 input rows -------------------
  float4v acc[2][4][2];
#pragma unroll
  for (int o = 0; o < 2; ++o)
#pragma unroll
    for (int ml = 0; ml < 4; ++ml)
#pragma unroll
      for (int nl = 0; nl < 2; ++nl) acc[o][ml][nl] = float4v{0.f, 0.f, 0.f, 0.f};

  const int jbase = wm * 64 + lr;
#pragma unroll
  for (int s = 0; s < 6; ++s) {
    const int kw    = s >> 1;
    const int half  = s & 1;
    const int cslot = half * 4 + lg;
    const int jlow  = (lr + kw) & 7;
    const int base_s = (jbase + kw) * 128 + ((cslot * 16) ^ (jlow << 4));
    short8v bfr[3][2];
#pragma unroll
    for (int r = 0; r < 4; ++r) {
      short8v a[4];
#pragma unroll
      for (int ml = 0; ml < 4; ++ml)
        a[ml] = *reinterpret_cast<const short8v*>(xT + base_s + r * 16640 + ml * 2048);
      if (r < 3) {   // load B-frags for kh=r (serve o=0 now, o=1 at r+1)
        const int fi = (r * 6 + s) * 8 + wn * 2;
        bfr[r][0] = *reinterpret_cast<const short8v*>(wf + (size_t)(fi + 0) * 512 + l * 8);
        bfr[r][1] = *reinterpret_cast<const short8v*>(wf + (size_t)(fi + 1) * 512 + l * 8);
#pragma unroll
        for (int ml = 0; ml < 4; ++ml)
#pragma unroll
          for (int nl = 0; nl < 2; ++nl)
            acc[0][ml][nl] = __builtin_amdgcn_mfma_f32_16x16x32_bf16(
                a[ml], bfr[r][nl], acc[0][ml][nl], 0, 0, 0);
      }
      if (r >= 1) {  // o=1, kh=r-1
#pragma unroll
        for (int ml = 0; ml < 4; ++ml)
#pragma unroll
          for (int nl = 0; nl < 2; ++nl)
            acc[1][ml][nl] = __builtin_amdgcn_mfma_f32_16x16x32_bf16(
                a[ml], bfr[r - 1][nl], acc[1][ml][nl], 0, 0, 0);
      }
    }
  }

  // ---- epilogue: out = copysign(exp2(fma(pe, log2|s|, pl)), s) + bias -----
#pragma unroll
  for (int o = 0; o < 2; ++o) {
    const int oh = h0 + o;
#pragma unroll
    for (int ml = 0; ml < 4; ++ml) {
      const int w0 = wm * 64 + ml * 16 + lg * 4;
      const float4v plv = *reinterpret_cast<const float4v*>(&pl[o][w0]);
#pragma unroll
      for (int nl = 0; nl < 2; ++nl) {
        const int n  = wn * 32 + nl * 16 + lr;
        const float bv = bias[n];
        float4v ov;
#pragma unroll
        for (int r = 0; r < 4; ++r) {
          const float sv  = acc[o][ml][nl][r];
          const float lg2 = __builtin_amdgcn_logf(fabsf(sv));   // abs folds into v_log
          const float e   = __builtin_amdgcn_exp2f(fmaf(pe, lg2, plv[r]));
          ov[r] = copysignf(e, sv) + bv;
        }
        *reinterpret_cast<float4v*>(
            out + (((size_t)b * C_OUT + n) * H_N + oh) * W_N + w0) = ov;
      }
    }
  }
}

// ---------------------------------------------------------------------------
extern "C" void kernel_launch(void* const* d_in, const int* in_sizes, int n_in,
                              void* d_out, int out_size, void* d_ws, size_t ws_size,
                              hipStream_t stream) {
  const float* x = (const float*)d_in[0];
  const float* w = (const float*)d_in[1];
  const float* b = (const float*)d_in[2];
  const float* q = (const float*)d_in[3];
  const float* p = (const float*)d_in[4];
  float* out = (float*)d_out;
  float* partial = (float*)d_ws;                               // 36 floats
  unsigned short* wf = (unsigned short*)((char*)d_ws + 256);   // 144KB B-frags

  scs_prep_w<<<36, 256, 0, stream>>>(w, wf, partial);
  scs_main<<<B_N * (H_N / 2), 512, 0, stream>>>(x, wf, b, q, p, partial, out);
}